// Round 1
// baseline (14.528 us; speedup 1.0000x reference)
//
#include <hip/hip_runtime.h>

__device__ __forceinline__ void mm4(const float A[4][4], const float B[4][4], float C[4][4]) {
#pragma unroll
  for (int i = 0; i < 4; ++i) {
#pragma unroll
    for (int j = 0; j < 4; ++j) {
      float s = A[i][0] * B[0][j];
      s = fmaf(A[i][1], B[1][j], s);
      s = fmaf(A[i][2], B[2][j], s);
      s = fmaf(A[i][3], B[3][j], s);
      C[i][j] = s;
    }
  }
}

__global__ __launch_bounds__(256) void brick_wall_kernel(
    const float* __restrict__ pcpa,
    const float* __restrict__ cov,
    const float* __restrict__ upd,
    const float* __restrict__ chi,
    const int* __restrict__ layer_ptr,
    float* __restrict__ out,
    int g, int S)
{
  const int tid = blockIdx.x * blockDim.x + threadIdx.x;
  if (tid >= 6 * g) return;
  const int p = tid / g;          // g % 64 == 0 -> p is wave-uniform
  const int q = tid - p * g;

  const bool even = ((layer_ptr[0] & 1) == 0);
  const int gq = even ? g : (g - 1);
  if (q >= gq) return;
  const int base = even ? (4 * q) : (4 * q + 2);

  // ---- E = 4*(mc - mc^T) from chi (antisymmetric 4x4) ----
  const float* cq = chi + 6 * q;
  const float x0 = cq[0], x1 = cq[1], x2 = cq[2], x3 = cq[3], x4 = cq[4], x5 = cq[5];
  float A[4][4];
  A[0][0] = 0.f;       A[0][1] = -2.f * x4; A[0][2] =  2.f * x2; A[0][3] =  2.f * x3;
  A[1][0] =  2.f * x4; A[1][1] = 0.f;       A[1][2] = -2.f * x0; A[1][3] = -2.f * x1;
  A[2][0] = -2.f * x2; A[2][1] =  2.f * x0; A[2][2] = 0.f;       A[2][3] = -2.f * x5;
  A[3][0] = -2.f * x3; A[3][1] =  2.f * x1; A[3][2] =  2.f * x5; A[3][3] = 0.f;

  // ---- scaling: ||M||_inf <= max rowsum|E| + 2 (D rowsum) ----
  const float r0 = fabsf(A[0][1]) + fabsf(A[0][2]) + fabsf(A[0][3]);
  const float r1 = fabsf(A[1][0]) + fabsf(A[1][2]) + fabsf(A[1][3]);
  const float r2 = fabsf(A[2][0]) + fabsf(A[2][1]) + fabsf(A[2][3]);
  const float r3 = fabsf(A[3][0]) + fabsf(A[3][1]) + fabsf(A[3][2]);
  const float nrm = fmaxf(fmaxf(r0, r1), fmaxf(r2, r3)) + 2.f;

  int sq = 0;
  float sc = 1.f;
  while (nrm * sc > 0.5f && sq < 24) { ++sq; sc *= 0.5f; }

#pragma unroll
  for (int i = 0; i < 4; ++i)
#pragma unroll
    for (int j = 0; j < 4; ++j) A[i][j] *= sc;

  // ---- D_p (4*PHC[p]), scaled; constant indices only (no scratch) ----
  float D[4][4];
#pragma unroll
  for (int i = 0; i < 4; ++i)
#pragma unroll
    for (int j = 0; j < 4; ++j) D[i][j] = 0.f;
  const float v = 2.f * sc;
  switch (p) {
    case 0: D[1][2] = -v; D[2][1] =  v; break;
    case 1: D[1][3] = -v; D[3][1] =  v; break;
    case 2: D[0][2] =  v; D[2][0] = -v; break;
    case 3: D[0][3] =  v; D[3][0] = -v; break;
    case 4: D[0][1] = -v; D[1][0] =  v; break;
    default: D[2][3] = -v; D[3][2] =  v; break;
  }

  // ---- Taylor for exp([[A,D],[0,A]]) = [[X,Y],[0,X]] ----
  // T_n = A T_{n-1}/n ; U_n = (A U_{n-1} + D T_{n-1})/n ; X=SUM T, Y=SUM U
  float X[4][4], Y[4][4], T[4][4], U[4][4];
#pragma unroll
  for (int i = 0; i < 4; ++i)
#pragma unroll
    for (int j = 0; j < 4; ++j) {
      const float id = (i == j) ? 1.f : 0.f;
      X[i][j] = id; T[i][j] = id;
      Y[i][j] = 0.f; U[i][j] = 0.f;
    }

  for (int n = 1; n <= 12; ++n) {
    const float rn = 1.f / (float)n;
    float Un[4][4], Tn[4][4];
#pragma unroll
    for (int i = 0; i < 4; ++i)
#pragma unroll
      for (int j = 0; j < 4; ++j) {
        float acc = A[i][0] * U[0][j];
        acc = fmaf(A[i][1], U[1][j], acc);
        acc = fmaf(A[i][2], U[2][j], acc);
        acc = fmaf(A[i][3], U[3][j], acc);
        acc = fmaf(D[i][0], T[0][j], acc);
        acc = fmaf(D[i][1], T[1][j], acc);
        acc = fmaf(D[i][2], T[2][j], acc);
        acc = fmaf(D[i][3], T[3][j], acc);
        Un[i][j] = acc * rn;
      }
    mm4(A, T, Tn);
#pragma unroll
    for (int i = 0; i < 4; ++i)
#pragma unroll
      for (int j = 0; j < 4; ++j) {
        T[i][j] = Tn[i][j] * rn;
        U[i][j] = Un[i][j];
        X[i][j] += T[i][j];
        Y[i][j] += U[i][j];
      }
  }

  // ---- squaring: (X,Y) -> (X^2, XY + YX), sq times ----
  for (int k = 0; k < sq; ++k) {
    float XY[4][4], YX[4][4], XX[4][4];
    mm4(X, Y, XY);
    mm4(Y, X, YX);
    mm4(X, X, XX);
#pragma unroll
    for (int i = 0; i < 4; ++i)
#pragma unroll
      for (int j = 0; j < 4; ++j) {
        Y[i][j] = XY[i][j] + YX[i][j];
        X[i][j] = XX[i][j];
      }
  }
  // Y is now dR = expm(M)[0:4, 4:8]

  // ---- load diagonal 4x4 blocks of cov (C) and upd (R) ----
  float Cb[4][4], Rb[4][4];
  const size_t boff = (size_t)base * (size_t)S + (size_t)base;
  if (even) {
    // 16B-aligned (base multiple of 4)
#pragma unroll
    for (int i = 0; i < 4; ++i) {
      const float4 rr = *reinterpret_cast<const float4*>(upd + boff + (size_t)i * S);
      const float4 cc = *reinterpret_cast<const float4*>(cov + boff + (size_t)i * S);
      Rb[i][0] = rr.x; Rb[i][1] = rr.y; Rb[i][2] = rr.z; Rb[i][3] = rr.w;
      Cb[i][0] = cc.x; Cb[i][1] = cc.y; Cb[i][2] = cc.z; Cb[i][3] = cc.w;
    }
  } else {
    // base = 4q+2: not float4-aligned, scalar loads
#pragma unroll
    for (int i = 0; i < 4; ++i)
#pragma unroll
      for (int j = 0; j < 4; ++j) {
        Rb[i][j] = upd[boff + (size_t)i * S + j];
        Cb[i][j] = cov[boff + (size_t)i * S + j];
      }
  }

  // ---- F = dR @ R^T ----
  float F[4][4];
#pragma unroll
  for (int i = 0; i < 4; ++i)
#pragma unroll
    for (int j = 0; j < 4; ++j) {
      float s = Y[i][0] * Rb[j][0];
      s = fmaf(Y[i][1], Rb[j][1], s);
      s = fmaf(Y[i][2], Rb[j][2], s);
      s = fmaf(Y[i][3], Rb[j][3], s);
      F[i][j] = s;
    }

  // ---- comm = F C - C F ; need [1][0] and [3][2] ----
  float comm10 = 0.f, comm32 = 0.f;
#pragma unroll
  for (int k = 0; k < 4; ++k) {
    comm10 += F[1][k] * Cb[k][0] - Cb[1][k] * F[k][0];
    comm32 += F[3][k] * Cb[k][2] - Cb[3][k] * F[k][2];
  }

  out[p * gq + q] = comm10 * pcpa[2 * q] + comm32 * pcpa[2 * q + 1];
}

extern "C" void kernel_launch(void* const* d_in, const int* in_sizes, int n_in,
                              void* d_out, int out_size, void* d_ws, size_t ws_size,
                              hipStream_t stream) {
  const float* pcpa = (const float*)d_in[0];
  const float* cov  = (const float*)d_in[1];
  const float* upd  = (const float*)d_in[2];
  const float* chi  = (const float*)d_in[3];
  const int*   layer = (const int*)d_in[6];
  float* out = (float*)d_out;

  const int num_qubits = in_sizes[0];
  const int S = 2 * num_qubits;
  const int g = in_sizes[3] / 6;

  const int total = 6 * g;
  const int block = 256;
  const int grid = (total + block - 1) / block;
  brick_wall_kernel<<<grid, block, 0, stream>>>(pcpa, cov, upd, chi, layer, out, g, S);
}

// Round 2
// 13.106 us; speedup vs baseline: 1.1085x; 1.1085x over previous
//
#include <hip/hip_runtime.h>

__device__ __forceinline__ void mm4(const float A[4][4], const float B[4][4], float C[4][4]) {
#pragma unroll
  for (int i = 0; i < 4; ++i) {
#pragma unroll
    for (int j = 0; j < 4; ++j) {
      float s = A[i][0] * B[0][j];
      s = fmaf(A[i][1], B[1][j], s);
      s = fmaf(A[i][2], B[2][j], s);
      s = fmaf(A[i][3], B[3][j], s);
      C[i][j] = s;
    }
  }
}

// Y = top-right 4x4 block of exp([[A,D],[0,A]]) after scaling by 2^-sq outside
// and `sq` squarings here. D is sparse: D[RA][RB] = +w, D[RB][RA] = -w.
// Recurrence: T_n = A T_{n-1}/n ; U_n = (A U_{n-1} + D T_{n-1})/n
// X = sum T (= e^A), Y = sum U (= Frechet derivative block).
// Squaring step: (X, Y) -> (X^2, XY + YX).
template<int RA, int RB>
__device__ __forceinline__ void frechet_expm(const float A[4][4], float w, int sq, float Y[4][4]) {
  float X[4][4], T[4][4], U[4][4];
#pragma unroll
  for (int i = 0; i < 4; ++i)
#pragma unroll
    for (int j = 0; j < 4; ++j) {
      const float id = (i == j) ? 1.f : 0.f;
      X[i][j] = id; T[i][j] = id; U[i][j] = 0.f; Y[i][j] = 0.f;
    }

  for (int n = 1; n <= 10; ++n) {
    const float rn = 1.f / (float)n;
    float Un[4][4], Tn[4][4];
    // dense A·U
#pragma unroll
    for (int i = 0; i < 4; ++i)
#pragma unroll
      for (int j = 0; j < 4; ++j) {
        float acc = A[i][0] * U[0][j];
        acc = fmaf(A[i][1], U[1][j], acc);
        acc = fmaf(A[i][2], U[2][j], acc);
        acc = fmaf(A[i][3], U[3][j], acc);
        Un[i][j] = acc;
      }
    // sparse D·T: only rows RA (+w * T[RB][:]) and RB (-w * T[RA][:])
#pragma unroll
    for (int j = 0; j < 4; ++j) {
      Un[RA][j] = fmaf( w, T[RB][j], Un[RA][j]);
      Un[RB][j] = fmaf(-w, T[RA][j], Un[RB][j]);
    }
    mm4(A, T, Tn);
#pragma unroll
    for (int i = 0; i < 4; ++i)
#pragma unroll
      for (int j = 0; j < 4; ++j) {
        T[i][j] = Tn[i][j] * rn;
        U[i][j] = Un[i][j] * rn;
        X[i][j] += T[i][j];
        Y[i][j] += U[i][j];
      }
  }

  for (int k = 0; k < sq; ++k) {
    float XY[4][4], YX[4][4];
    mm4(X, Y, XY);
    mm4(Y, X, YX);
    if (k + 1 < sq) {   // X is dead after the last squaring: skip final X^2
      float XX[4][4];
      mm4(X, X, XX);
#pragma unroll
      for (int i = 0; i < 4; ++i)
#pragma unroll
        for (int j = 0; j < 4; ++j) X[i][j] = XX[i][j];
    }
#pragma unroll
    for (int i = 0; i < 4; ++i)
#pragma unroll
      for (int j = 0; j < 4; ++j) Y[i][j] = XY[i][j] + YX[i][j];
  }
}

__global__ __launch_bounds__(256) void brick_wall_kernel(
    const float* __restrict__ pcpa,
    const float* __restrict__ cov,
    const float* __restrict__ upd,
    const float* __restrict__ chi,
    const int* __restrict__ layer_ptr,
    float* __restrict__ out,
    int g, int S)
{
  const int tid = blockIdx.x * blockDim.x + threadIdx.x;
  const int p = tid / g;          // g % 256 == 0 -> p is block-uniform
  const int q = tid - p * g;

  const bool even = ((layer_ptr[0] & 1) == 0);
  const int gq = even ? g : (g - 1);
  const bool valid = (q < gq);
  const int qc = valid ? q : 0;   // clamp; no early return (wave shfl below)
  const int base = even ? (4 * qc) : (4 * qc + 2);

  // ---- hoisted global loads: issue before the long VALU chain ----
  float Cb[4][4], Rb[4][4];
  const size_t boff = (size_t)base * (size_t)S + (size_t)base;
  if (even) {
#pragma unroll
    for (int i = 0; i < 4; ++i) {
      const float4 rr = *reinterpret_cast<const float4*>(upd + boff + (size_t)i * S);
      const float4 cc = *reinterpret_cast<const float4*>(cov + boff + (size_t)i * S);
      Rb[i][0] = rr.x; Rb[i][1] = rr.y; Rb[i][2] = rr.z; Rb[i][3] = rr.w;
      Cb[i][0] = cc.x; Cb[i][1] = cc.y; Cb[i][2] = cc.z; Cb[i][3] = cc.w;
    }
  } else {
#pragma unroll
    for (int i = 0; i < 4; ++i)
#pragma unroll
      for (int j = 0; j < 4; ++j) {
        Rb[i][j] = upd[boff + (size_t)i * S + j];
        Cb[i][j] = cov[boff + (size_t)i * S + j];
      }
  }
  const float pe = pcpa[2 * qc];
  const float po = pcpa[2 * qc + 1];

  // ---- E = 4*(mc - mc^T) from chi (antisymmetric 4x4) ----
  const float* cq = chi + 6 * qc;
  const float x0 = cq[0], x1 = cq[1], x2 = cq[2], x3 = cq[3], x4 = cq[4], x5 = cq[5];

  // inf-norm bound of M = [[A,D],[0,A]]: max rowsum(|A|) + rowsum(|D|)=2
  const float a0 = fabsf(x0), a1 = fabsf(x1), a2 = fabsf(x2),
              a3 = fabsf(x3), a4 = fabsf(x4), a5 = fabsf(x5);
  const float r0 = a4 + a2 + a3;
  const float r1 = a4 + a0 + a1;
  const float r2 = a2 + a0 + a5;
  const float r3 = a3 + a1 + a5;
  float nrm = 2.f * fmaxf(fmaxf(r0, r1), fmaxf(r2, r3)) + 2.f;

  // wave-uniform squaring count (all 64 lanes active by construction)
#pragma unroll
  for (int o = 32; o > 0; o >>= 1) nrm = fmaxf(nrm, __shfl_xor(nrm, o, 64));
  int e;
  (void)frexpf(nrm, &e);          // nrm = m * 2^e, m in [0.5,1) -> nrm < 2^e
  const int sq = (e > 0) ? ((e < 16) ? e : 16) : 0;   // nrm * 2^-sq <= 1
  const float sc = ldexpf(1.f, -sq);

  float A[4][4];
  const float y0 = 2.f * sc * x0, y1 = 2.f * sc * x1, y2 = 2.f * sc * x2,
              y3 = 2.f * sc * x3, y4 = 2.f * sc * x4, y5 = 2.f * sc * x5;
  A[0][0] = 0.f; A[0][1] = -y4;  A[0][2] =  y2;  A[0][3] =  y3;
  A[1][0] =  y4; A[1][1] = 0.f;  A[1][2] = -y0;  A[1][3] = -y1;
  A[2][0] = -y2; A[2][1] =  y0;  A[2][2] = 0.f;  A[2][3] = -y5;
  A[3][0] = -y3; A[3][1] =  y1;  A[3][2] =  y5;  A[3][3] = 0.f;

  // D_p = 4*PHC[p] scaled: two nonzeros +-v at positions per p (block-uniform)
  const float v = 2.f * sc;
  float Y[4][4];
  if      (p == 0) frechet_expm<1, 2>(A, -v, sq, Y);
  else if (p == 1) frechet_expm<1, 3>(A, -v, sq, Y);
  else if (p == 2) frechet_expm<0, 2>(A,  v, sq, Y);
  else if (p == 3) frechet_expm<0, 3>(A,  v, sq, Y);
  else if (p == 4) frechet_expm<0, 1>(A, -v, sq, Y);
  else             frechet_expm<2, 3>(A, -v, sq, Y);
  // Y = dR = expm(M)[0:4, 4:8]

  // ---- F = dR @ R^T ----
  float F[4][4];
#pragma unroll
  for (int i = 0; i < 4; ++i)
#pragma unroll
    for (int j = 0; j < 4; ++j) {
      float s = Y[i][0] * Rb[j][0];
      s = fmaf(Y[i][1], Rb[j][1], s);
      s = fmaf(Y[i][2], Rb[j][2], s);
      s = fmaf(Y[i][3], Rb[j][3], s);
      F[i][j] = s;
    }

  // ---- comm = F C - C F ; need [1][0] and [3][2] ----
  float comm10 = 0.f, comm32 = 0.f;
#pragma unroll
  for (int k = 0; k < 4; ++k) {
    comm10 += F[1][k] * Cb[k][0] - Cb[1][k] * F[k][0];
    comm32 += F[3][k] * Cb[k][2] - Cb[3][k] * F[k][2];
  }

  if (valid) out[p * gq + qc] = comm10 * pe + comm32 * po;
}

extern "C" void kernel_launch(void* const* d_in, const int* in_sizes, int n_in,
                              void* d_out, int out_size, void* d_ws, size_t ws_size,
                              hipStream_t stream) {
  const float* pcpa = (const float*)d_in[0];
  const float* cov  = (const float*)d_in[1];
  const float* upd  = (const float*)d_in[2];
  const float* chi  = (const float*)d_in[3];
  const int*   layer = (const int*)d_in[6];
  float* out = (float*)d_out;

  const int num_qubits = in_sizes[0];
  const int S = 2 * num_qubits;
  const int g = in_sizes[3] / 6;

  const int total = 6 * g;
  const int block = 256;
  const int grid = (total + block - 1) / block;
  brick_wall_kernel<<<grid, block, 0, stream>>>(pcpa, cov, upd, chi, layer, out, g, S);
}

// Round 3
// 9.357 us; speedup vs baseline: 1.5527x; 1.4007x over previous
//
#include <hip/hip_runtime.h>

__global__ __launch_bounds__(256) void brick_wall_kernel(
    const float* __restrict__ pcpa,
    const float* __restrict__ cov,
    const float* __restrict__ upd,
    const float* __restrict__ chi,
    const int* __restrict__ layer_ptr,
    float* __restrict__ out,
    int g, int S)
{
  const int tid = blockIdx.x * blockDim.x + threadIdx.x;
  if (tid >= 6 * g) return;
  const int p = tid / g;          // g % 256 == 0 -> p is block-uniform
  const int q = tid - p * g;

  const bool even = ((layer_ptr[0] & 1) == 0);
  const int gq = even ? g : (g - 1);
  if (q >= gq) return;
  const int base = even ? (4 * q) : (4 * q + 2);

  // ---- hoisted global loads (issue before the trig/VALU chain) ----
  float Cb[4][4], Rb[4][4];
  const size_t boff = (size_t)base * (size_t)S + (size_t)base;
  if (even) {
#pragma unroll
    for (int i = 0; i < 4; ++i) {
      const float4 rr = *reinterpret_cast<const float4*>(upd + boff + (size_t)i * S);
      const float4 cc = *reinterpret_cast<const float4*>(cov + boff + (size_t)i * S);
      Rb[i][0] = rr.x; Rb[i][1] = rr.y; Rb[i][2] = rr.z; Rb[i][3] = rr.w;
      Cb[i][0] = cc.x; Cb[i][1] = cc.y; Cb[i][2] = cc.z; Cb[i][3] = cc.w;
    }
  } else {
#pragma unroll
    for (int i = 0; i < 4; ++i)
#pragma unroll
      for (int j = 0; j < 4; ++j) {
        Rb[i][j] = upd[boff + (size_t)i * S + j];
        Cb[i][j] = cov[boff + (size_t)i * S + j];
      }
  }
  const float pe = pcpa[2 * q];
  const float po = pcpa[2 * q + 1];

  const float* cq = chi + 6 * q;
  const float x0 = cq[0], x1 = cq[1], x2 = cq[2], x3 = cq[3], x4 = cq[4], x5 = cq[5];

  // A = E entries: a01=-2x4 a02=2x2 a03=2x3 a12=-2x0 a13=-2x1 a23=-2x5
  // so(4)=su(2)+ (+) su(2)-:  u=((a01+a23),(a02-a13),(a03+a12))/2, v=((a01-a23),(a02+a13),(a03-a12))/2
  const float u1 = -(x4 + x5), u2 = x2 + x1, u3 = x3 - x0;
  const float v1 =  x5 - x4,   v2 = x2 - x1, v3 = x3 + x0;

  // D = 4*PHC[p]: dual decomposition gives unit-axis d+ / d- (block-uniform p)
  float du1 = 0.f, du2 = 0.f, du3 = 0.f, dv1 = 0.f, dv2 = 0.f, dv3 = 0.f;
  switch (p) {
    case 0: du3 = -1.f; dv3 =  1.f; break;  // a12=-2
    case 1: du2 =  1.f; dv2 = -1.f; break;  // a13=-2
    case 2: du2 =  1.f; dv2 =  1.f; break;  // a02=+2
    case 3: du3 =  1.f; dv3 =  1.f; break;  // a03=+2
    case 4: du1 = -1.f; dv1 = -1.f; break;  // a01=-2
    default: du1 = -1.f; dv1 =  1.f; break; // a23=-2
  }

  // ---- + sector: angle nu=|u|; exp coeffs (cu, su=sin/nu); Ad-integral coeffs
  // alpha = sin(2nu)/(2nu) = su*cu ; beta = (1-cos(2nu))/(2nu) = su*sin
  const float nnu = u1*u1 + u2*u2 + u3*u3;
  const float nu  = sqrtf(nnu);
  const float su_s = __sinf(nu), cu = __cosf(nu);
  const bool  tu  = (nnu < 1e-16f);
  const float su  = tu ? 1.f : (su_s / nu);
  const float au  = tu ? 1.f : (su * cu);
  const float bu  = tu ? 0.f : (su * su_s);
  const float inu = tu ? 0.f : (1.f / nu);
  const float n1 = u1 * inu, n2 = u2 * inu, n3 = u3 * inu;

  // ---- - sector (rotation sense flipped -> minus on the cross term)
  const float nnv = v1*v1 + v2*v2 + v3*v3;
  const float nv  = sqrtf(nnv);
  const float sv_s = __sinf(nv), cv = __cosf(nv);
  const bool  tv  = (nnv < 1e-16f);
  const float sv  = tv ? 1.f : (sv_s / nv);
  const float av  = tv ? 1.f : (sv * cv);
  const float bv  = tv ? 0.f : (sv * sv_s);
  const float inv = tv ? 0.f : (1.f / nv);
  const float m1 = v1 * inv, m2 = v2 * inv, m3 = v3 * inv;

  // Phi+ = (1-au)(n.d)n + au d + bu (n x d)
  const float dotu = n1*du1 + n2*du2 + n3*du3;
  const float ku = (1.f - au) * dotu;
  const float wu1 = ku*n1 + au*du1 + bu*(n2*du3 - n3*du2);
  const float wu2 = ku*n2 + au*du2 + bu*(n3*du1 - n1*du3);
  const float wu3 = ku*n3 + au*du3 + bu*(n1*du2 - n2*du1);
  // Phi- = (1-av)(m.d)m + av d - bv (m x d)
  const float dotv = m1*dv1 + m2*dv2 + m3*dv3;
  const float kv = (1.f - av) * dotv;
  const float wv1 = kv*m1 + av*dv1 - bv*(m2*dv3 - m3*dv2);
  const float wv2 = kv*m2 + av*dv2 - bv*(m3*dv1 - m1*dv3);
  const float wv3 = kv*m3 + av*dv3 - bv*(m1*dv2 - m2*dv1);

  // XL = cu*I + su*Aplus(u); XR = cv*I + sv*Aminus(v)
  // Aplus(w)  = [[0,w1,w2,w3],[-w1,0,w3,-w2],[-w2,-w3,0,w1],[-w3,w2,-w1,0]]
  // Aminus(w) = [[0,w1,w2,w3],[-w1,0,-w3,w2],[-w2,w3,0,-w1],[-w3,-w2,w1,0]]
  const float p1 = su*u1, p2 = su*u2, p3 = su*u3;
  const float q1 = sv*v1, q2 = sv*v2, q3 = sv*v3;
  const float XL[4][4] = {
    { cu,  p1,  p2,  p3},
    {-p1,  cu,  p3, -p2},
    {-p2, -p3,  cu,  p1},
    {-p3,  p2, -p1,  cu}};
  const float XR[4][4] = {
    { cv,  q1,  q2,  q3},
    {-q1,  cv, -q3,  q2},
    {-q2,  q3,  cv, -q1},
    {-q3, -q2,  q1,  cv}};
  // Phi = Aplus(wu) + Aminus(wv)
  const float f01 = wu1 + wv1, f02 = wu2 + wv2, f03 = wu3 + wv3;
  const float f12 = wu3 - wv3, f13 = -wu2 + wv2, f23 = wu1 - wv1;
  const float Ph[4][4] = {
    { 0.f,  f01,  f02,  f03},
    {-f01,  0.f,  f12,  f13},
    {-f02, -f12,  0.f,  f23},
    {-f03, -f13, -f23,  0.f}};

  // X = XL @ XR
  float X[4][4];
#pragma unroll
  for (int i = 0; i < 4; ++i)
#pragma unroll
    for (int j = 0; j < 4; ++j) {
      float s = XL[i][0] * XR[0][j];
      s = fmaf(XL[i][1], XR[1][j], s);
      s = fmaf(XL[i][2], XR[2][j], s);
      s = fmaf(XL[i][3], XR[3][j], s);
      X[i][j] = s;
    }
  // Y = X @ Phi   (= expm(M)[0:4,4:8])
  float Y[4][4];
#pragma unroll
  for (int i = 0; i < 4; ++i)
#pragma unroll
    for (int j = 0; j < 4; ++j) {
      float s = X[i][0] * Ph[0][j];
      s = fmaf(X[i][1], Ph[1][j], s);
      s = fmaf(X[i][2], Ph[2][j], s);
      s = fmaf(X[i][3], Ph[3][j], s);
      Y[i][j] = s;
    }

  // F = Y @ R^T
  float F[4][4];
#pragma unroll
  for (int i = 0; i < 4; ++i)
#pragma unroll
    for (int j = 0; j < 4; ++j) {
      float s = Y[i][0] * Rb[j][0];
      s = fmaf(Y[i][1], Rb[j][1], s);
      s = fmaf(Y[i][2], Rb[j][2], s);
      s = fmaf(Y[i][3], Rb[j][3], s);
      F[i][j] = s;
    }

  // comm = F C - C F ; need [1][0] and [3][2]
  float comm10 = 0.f, comm32 = 0.f;
#pragma unroll
  for (int k = 0; k < 4; ++k) {
    comm10 += F[1][k] * Cb[k][0] - Cb[1][k] * F[k][0];
    comm32 += F[3][k] * Cb[k][2] - Cb[3][k] * F[k][2];
  }

  out[p * gq + q] = comm10 * pe + comm32 * po;
}

extern "C" void kernel_launch(void* const* d_in, const int* in_sizes, int n_in,
                              void* d_out, int out_size, void* d_ws, size_t ws_size,
                              hipStream_t stream) {
  const float* pcpa = (const float*)d_in[0];
  const float* cov  = (const float*)d_in[1];
  const float* upd  = (const float*)d_in[2];
  const float* chi  = (const float*)d_in[3];
  const int*   layer = (const int*)d_in[6];
  float* out = (float*)d_out;

  const int num_qubits = in_sizes[0];
  const int S = 2 * num_qubits;
  const int g = in_sizes[3] / 6;

  const int total = 6 * g;
  const int block = 256;
  const int grid = (total + block - 1) / block;
  brick_wall_kernel<<<grid, block, 0, stream>>>(pcpa, cov, upd, chi, layer, out, g, S);
}